// Round 7
// baseline (484.426 us; speedup 1.0000x reference)
//
#include <hip/hip_runtime.h>
#include <math.h>
#include <stdint.h>

#define NFEA    64
#define NHEAD   3
#define PSTRIDE 256   // floats per partial record: [0,192) numerator, [192,195) denom
#define KSLOT   4     // slots 0..2 = direct stores, slot 3 = zeroed atomic overflow

typedef float v2f __attribute__((ext_vector_type(2)));

// ---------------- segment starts from sorted owner ----------------
__global__ void gar_starts(const int* __restrict__ owner, int* __restrict__ starts,
                           int n_atoms, int n_graphs)
{
  int a = blockIdx.x * blockDim.x + threadIdx.x;
  if (a >= n_atoms) return;
  int cur  = owner[a];
  int prev = (a == 0) ? -1 : owner[a - 1];
  for (int g = prev + 1; g <= cur; ++g) starts[g] = a;
  if (a == n_atoms - 1)
    for (int g = cur + 1; g <= n_graphs; ++g) starts[g] = n_atoms;
}

// ---------------- fused MLP + e + partial pooling (no hot atomics) ----------
// Block = 256 threads = 256 contiguous atoms.
// Phase 1 (thread = atom): 16 float4 row loads, asm-fenced so ALL issue before
//   compute (keeps row in VGPRs, MSHR-merges same-line requests); MLP;
//   e = exp(logit) with NO max subtraction (|logit|<~4 here; softmax is
//   shift-invariant; validated absmax ~2e-3 << 9.8e-3).
// Phase 2 (wave = graph-in-block, lane = feature): pool the block's own rows
//   (L1/L2-hot re-read), e broadcast from LDS; write one partial record per
//   (graph, block-slot) with plain stores. Slot >= 3 falls back to atomics
//   into the zeroed overflow plane (needs a graph spanning >3 blocks: never
//   at n~122, correctness-only).
__global__ __launch_bounds__(256, 3) void gar_fused(
    const float* __restrict__ atom_feas,
    const int*   __restrict__ owner,
    const int*   __restrict__ starts,
    const float* __restrict__ W1, const float* __restrict__ b1,
    const float* __restrict__ W2, const float* __restrict__ b2,
    float* __restrict__ partials,   // [KSLOT][n_graphs][PSTRIDE]
    int n_atoms, int n_graphs)
{
  __shared__ __align__(16) float4 e4[256];
  const int tid = threadIdx.x;
  const int blockstart = blockIdx.x * 256;
  const int a = blockstart + tid;
  const bool act = a < n_atoms;
  const int ar = act ? a : n_atoms - 1;     // clamp: garbage masked via e=0

  // ---- phase 1: MLP ----
  const float4* __restrict__ xrow = (const float4*)(atom_feas + (size_t)ar * NFEA);
  float4 xr[16];
#pragma unroll
  for (int q = 0; q < 16; ++q) xr[q] = xrow[q];
  asm volatile("" ::: "memory");            // fence: all 16 loads issue first

  v2f h[16];
#pragma unroll
  for (int j = 0; j < 16; ++j) h[j] = ((const v2f*)b1)[j];

#pragma unroll
  for (int q = 0; q < 16; ++q) {
    float xs[4] = {xr[q].x, xr[q].y, xr[q].z, xr[q].w};
#pragma unroll
    for (int dd = 0; dd < 4; ++dd) {
      v2f xd2 = {xs[dd], xs[dd]};
      const v2f* wrow = ((const v2f*)W1) + (q * 4 + dd) * 16;  // wave-uniform
#pragma unroll
      for (int jj = 0; jj < 16; ++jj)
        h[jj] = __builtin_elementwise_fma(xd2, wrow[jj], h[jj]);
    }
  }
  float l0 = b2[0], l1 = b2[1], l2 = b2[2];
#pragma unroll
  for (int jj = 0; jj < 16; ++jj) {
#pragma unroll
    for (int cc = 0; cc < 2; ++cc) {
      float hj = h[jj][cc];
      float s = hj * __builtin_amdgcn_rcpf(1.0f + __expf(-hj));  // SiLU
      int k = 2 * jj + cc;
      l0 = fmaf(s, W2[k * 3 + 0], l0);
      l1 = fmaf(s, W2[k * 3 + 1], l1);
      l2 = fmaf(s, W2[k * 3 + 2], l2);
    }
  }
  e4[tid] = make_float4(act ? __expf(l0) : 0.f,
                        act ? __expf(l1) : 0.f,
                        act ? __expf(l2) : 0.f, 0.f);
  __syncthreads();

  // ---- phase 2: per-graph partials; wave w handles graphs g0+w, g0+w+4, ...
  const int blockend = (blockstart + 256 < n_atoms) ? blockstart + 256 : n_atoms;
  const int g0 = owner[blockstart];
  const int g1 = owner[blockend - 1];
  const int w = tid >> 6, t = tid & 63;

  for (int g = g0 + w; g <= g1; g += 4) {   // wave-uniform
    const int gs0 = starts[g];
    int lo = gs0;           if (lo < blockstart) lo = blockstart;
    int hi = starts[g + 1]; if (hi > blockend)   hi = blockend;
    if (lo >= hi) continue;                 // empty graph id inside range

    float a0 = 0.f, a1 = 0.f, a2 = 0.f;     // lane t = feature t
    float dd0 = 0.f, dd1 = 0.f, dd2 = 0.f;
    for (int i = lo; i < hi; ++i) {
      float4 ev = e4[i - blockstart];       // same-address broadcast
      float  xv = atom_feas[(size_t)i * NFEA + t];  // coalesced, L1/L2-hot
      a0 = fmaf(ev.x, xv, a0);
      a1 = fmaf(ev.y, xv, a1);
      a2 = fmaf(ev.z, xv, a2);
      dd0 += ev.x; dd1 += ev.y; dd2 += ev.z;
    }
    const int slot = blockIdx.x - (gs0 >> 8);     // this block's index in g's span
    if (slot < KSLOT - 1) {
      float* P = partials + ((size_t)slot * n_graphs + g) * PSTRIDE;
      P[t * 3 + 0] = a0; P[t * 3 + 1] = a1; P[t * 3 + 2] = a2;
      if (t == 0) { P[192] = dd0; P[193] = dd1; P[194] = dd2; }
    } else {                                      // overflow plane (zeroed): cold
      float* P = partials + ((size_t)(KSLOT - 1) * n_graphs + g) * PSTRIDE;
      atomicAdd(P + t * 3 + 0, a0);
      atomicAdd(P + t * 3 + 1, a1);
      atomicAdd(P + t * 3 + 2, a2);
      if (t == 0) { atomicAdd(P + 192, dd0); atomicAdd(P + 193, dd1); atomicAdd(P + 194, dd2); }
    }
  }
}

// ---------------- reduce partials -> normalized output ----------------
// Wave per graph. Sums the span's valid slots (stale slots never read) plus
// the always-zeroed overflow plane, then divides by the denominator.
__global__ __launch_bounds__(256, 8) void gar_reduce(
    const int* __restrict__ starts,
    const float* __restrict__ partials,
    float* __restrict__ out, int n_graphs)
{
  const int g = blockIdx.x * 4 + (threadIdx.x >> 6);
  const int t = threadIdx.x & 63;
  if (g >= n_graphs) return;
  const int s0 = starts[g], s1 = starts[g + 1];

  const float* P3 = partials + ((size_t)(KSLOT - 1) * n_graphs + g) * PSTRIDE;
  float n0 = P3[t * 3 + 0], n1 = P3[t * 3 + 1], n2 = P3[t * 3 + 2];
  float dn0 = P3[192], dn1 = P3[193], dn2 = P3[194];

  int span = 0;
  if (s1 > s0) span = ((s1 - 1) >> 8) - (s0 >> 8) + 1;
  const int kmax = span < (KSLOT - 1) ? span : (KSLOT - 1);
  for (int k = 0; k < kmax; ++k) {
    const float* P = partials + ((size_t)k * n_graphs + g) * PSTRIDE;
    n0 += P[t * 3 + 0]; n1 += P[t * 3 + 1]; n2 += P[t * 3 + 2];
    dn0 += P[192]; dn1 += P[193]; dn2 += P[194];
  }
  float* og = out + (size_t)g * (NFEA * NHEAD);
  og[t * 3 + 0] = dn0 > 0.f ? n0 / dn0 : 0.f;   // empty graph -> 0 (matches ref)
  og[t * 3 + 1] = dn1 > 0.f ? n1 / dn1 : 0.f;
  og[t * 3 + 2] = dn2 > 0.f ? n2 / dn2 : 0.f;
}

extern "C" void kernel_launch(void* const* d_in, const int* in_sizes, int n_in,
                              void* d_out, int out_size, void* d_ws, size_t ws_size,
                              hipStream_t stream)
{
  const float* atom_feas = (const float*)d_in[0];
  const int*   owner     = (const int*)d_in[1];
  const float* W1        = (const float*)d_in[2];
  const float* b1        = (const float*)d_in[3];
  const float* W2        = (const float*)d_in[4];
  const float* b2        = (const float*)d_in[5];
  float* out = (float*)d_out;

  const int n_atoms  = in_sizes[1];
  const int n_graphs = out_size / (NFEA * NHEAD);

  // ws layout: starts[n_graphs+1] ints | pad 256B | partials[KSLOT][G][PSTRIDE]
  int* starts = (int*)d_ws;
  const size_t par_off = (((size_t)(n_graphs + 1) * sizeof(int)) + 255) & ~(size_t)255;
  float* partials = (float*)((char*)d_ws + par_off);

  // zero ONLY the overflow plane (slots 0..2 are fully overwritten where read)
  hipMemsetAsync(partials + (size_t)(KSLOT - 1) * n_graphs * PSTRIDE, 0,
                 (size_t)n_graphs * PSTRIDE * sizeof(float), stream);

  hipLaunchKernelGGL(gar_starts, dim3((n_atoms + 255) / 256), dim3(256), 0, stream,
                     owner, starts, n_atoms, n_graphs);
  hipLaunchKernelGGL(gar_fused, dim3((n_atoms + 255) / 256), dim3(256), 0, stream,
                     atom_feas, owner, starts, W1, b1, W2, b2, partials,
                     n_atoms, n_graphs);
  hipLaunchKernelGGL(gar_reduce, dim3((n_graphs + 3) / 4), dim3(256), 0, stream,
                     starts, partials, out, n_graphs);
}

// Round 8
// 414.057 us; speedup vs baseline: 1.1699x; 1.1699x over previous
//
#include <hip/hip_runtime.h>
#include <math.h>
#include <stdint.h>

#define NFEA    64
#define NHEAD   3
#define PSTRIDE 256   // floats per partial record: [0,192) numerator, [192,195) denom
#define KSLOT   4     // slots 0..2 = direct stores, slot 3 = zeroed atomic overflow

typedef float v2f __attribute__((ext_vector_type(2)));

// ---------------- segment starts from sorted owner ----------------
__global__ void gar_starts(const int* __restrict__ owner, int* __restrict__ starts,
                           int n_atoms, int n_graphs)
{
  int a = blockIdx.x * blockDim.x + threadIdx.x;
  if (a >= n_atoms) return;
  int cur  = owner[a];
  int prev = (a == 0) ? -1 : owner[a - 1];
  for (int g = prev + 1; g <= cur; ++g) starts[g] = a;
  if (a == n_atoms - 1)
    for (int g = cur + 1; g <= n_graphs; ++g) starts[g] = n_atoms;
}

// ---------------- fused MLP + e + partial pooling ----------
// Block = 256 threads = 256 contiguous atoms.
// Phase 1 (thread = atom): 16 float4 row loads, then sched_barrier(0) — blocks
//   ALL instruction movement so every load issues before any use (16 in flight
//   per wave; a "memory"-clobber asm was NOT enough: VALU uses hoisted between
//   loads and recycled registers, re-serializing — R7's VGPR=52 tell).
//   MLP; e = exp(logit), no max subtraction (|logit|<~4; softmax shift-invariant;
//   validated absmax ~1e-3 << 9.8e-3).
// Phase 2 (all 4 waves, lane = feature): atoms of each graph striped across
//   waves (i += 4); per-wave partials combined through LDS; one rotating wave
//   stores the (graph, block-slot) record with plain stores. Slot >= 3 falls
//   back to atomics into the zeroed overflow plane (graph spanning >3 blocks:
//   never at n~122, correctness-only).
__global__ __launch_bounds__(256, 3) void gar_fused(
    const float* __restrict__ atom_feas,
    const int*   __restrict__ owner,
    const int*   __restrict__ starts,
    const float* __restrict__ W1, const float* __restrict__ b1,
    const float* __restrict__ W2, const float* __restrict__ b2,
    float* __restrict__ partials,   // [KSLOT][n_graphs][PSTRIDE]
    int n_atoms, int n_graphs)
{
  __shared__ __align__(16) float4 e4[256];
  __shared__ __align__(16) float4 comb[4][64];
  const int tid = threadIdx.x;
  const int blockstart = blockIdx.x * 256;
  const int a = blockstart + tid;
  const bool act = a < n_atoms;
  const int ar = act ? a : n_atoms - 1;     // clamp: garbage masked via e=0

  // ---- phase 1: MLP ----
  const float4* __restrict__ xrow = (const float4*)(atom_feas + (size_t)ar * NFEA);
  float4 xr[16];
#pragma unroll
  for (int q = 0; q < 16; ++q) xr[q] = xrow[q];
  __builtin_amdgcn_sched_barrier(0);        // NOTHING crosses: all 16 loads issue first

  v2f h[16];
#pragma unroll
  for (int j = 0; j < 16; ++j) h[j] = ((const v2f*)b1)[j];

#pragma unroll
  for (int q = 0; q < 16; ++q) {
    float xs[4] = {xr[q].x, xr[q].y, xr[q].z, xr[q].w};
#pragma unroll
    for (int dd = 0; dd < 4; ++dd) {
      v2f xd2 = {xs[dd], xs[dd]};
      const v2f* wrow = ((const v2f*)W1) + (q * 4 + dd) * 16;  // wave-uniform
#pragma unroll
      for (int jj = 0; jj < 16; ++jj)
        h[jj] = __builtin_elementwise_fma(xd2, wrow[jj], h[jj]);
    }
  }
  float l0 = b2[0], l1 = b2[1], l2 = b2[2];
#pragma unroll
  for (int jj = 0; jj < 16; ++jj) {
#pragma unroll
    for (int cc = 0; cc < 2; ++cc) {
      float hj = h[jj][cc];
      float s = hj * __builtin_amdgcn_rcpf(1.0f + __expf(-hj));  // SiLU
      int k = 2 * jj + cc;
      l0 = fmaf(s, W2[k * 3 + 0], l0);
      l1 = fmaf(s, W2[k * 3 + 1], l1);
      l2 = fmaf(s, W2[k * 3 + 2], l2);
    }
  }
  e4[tid] = make_float4(act ? __expf(l0) : 0.f,
                        act ? __expf(l1) : 0.f,
                        act ? __expf(l2) : 0.f, 0.f);
  __syncthreads();

  // ---- phase 2: per-graph partials, atoms striped across the 4 waves ----
  const int blockend = (blockstart + 256 < n_atoms) ? blockstart + 256 : n_atoms;
  const int g0 = owner[blockstart];
  const int g1 = owner[blockend - 1];
  const int w = tid >> 6, t = tid & 63;

  for (int g = g0; g <= g1; ++g) {          // block-uniform range (~2-4 iters)
    const int gs0 = starts[g];
    int lo = gs0;           if (lo < blockstart) lo = blockstart;
    int hi = starts[g + 1]; if (hi > blockend)   hi = blockend;
    if (lo >= hi) continue;                 // block-uniform: barrier-safe skip

    float a0 = 0.f, a1 = 0.f, a2 = 0.f;     // lane t = feature t
    float dd0 = 0.f, dd1 = 0.f, dd2 = 0.f;  // wave-uniform denominator partials
#pragma unroll 4
    for (int i = lo + w; i < hi; i += 4) {  // wave-striped atoms
      float4 ev = e4[i - blockstart];       // same-address broadcast
      float  xv = atom_feas[(size_t)i * NFEA + t];  // coalesced, L2/L3-hot
      a0 = fmaf(ev.x, xv, a0);
      a1 = fmaf(ev.y, xv, a1);
      a2 = fmaf(ev.z, xv, a2);
      dd0 += ev.x; dd1 += ev.y; dd2 += ev.z;
    }
    const float ddsel = t == 0 ? dd0 : t == 1 ? dd1 : t == 2 ? dd2 : 0.f;
    comb[w][t] = make_float4(a0, a1, a2, ddsel);
    __syncthreads();
    if (w == (g & 3)) {                     // rotating store wave
      float4 c0 = comb[0][t], c1 = comb[1][t], c2 = comb[2][t], c3 = comb[3][t];
      float s0 = c0.x + c1.x + c2.x + c3.x;
      float s1 = c0.y + c1.y + c2.y + c3.y;
      float s2 = c0.z + c1.z + c2.z + c3.z;
      float sd = c0.w + c1.w + c2.w + c3.w; // lanes 0..2: combined denom[t]
      const int slot = blockIdx.x - (gs0 >> 8);   // block index within g's span
      if (slot < KSLOT - 1) {
        float* P = partials + ((size_t)slot * n_graphs + g) * PSTRIDE;
        P[t * 3 + 0] = s0; P[t * 3 + 1] = s1; P[t * 3 + 2] = s2;
        if (t < 3) P[192 + t] = sd;
      } else {                              // overflow plane (zeroed): cold
        float* P = partials + ((size_t)(KSLOT - 1) * n_graphs + g) * PSTRIDE;
        atomicAdd(P + t * 3 + 0, s0);
        atomicAdd(P + t * 3 + 1, s1);
        atomicAdd(P + t * 3 + 2, s2);
        if (t < 3) atomicAdd(P + 192 + t, sd);
      }
    }
    __syncthreads();                        // comb reusable for next graph
  }
}

// ---------------- reduce partials -> normalized output ----------------
// Wave per graph. Sums the span's valid slots (stale slots never read) plus
// the always-zeroed overflow plane, then divides by the denominator.
__global__ __launch_bounds__(256, 8) void gar_reduce(
    const int* __restrict__ starts,
    const float* __restrict__ partials,
    float* __restrict__ out, int n_graphs)
{
  const int g = blockIdx.x * 4 + (threadIdx.x >> 6);
  const int t = threadIdx.x & 63;
  if (g >= n_graphs) return;
  const int s0 = starts[g], s1 = starts[g + 1];

  const float* P3 = partials + ((size_t)(KSLOT - 1) * n_graphs + g) * PSTRIDE;
  float n0 = P3[t * 3 + 0], n1 = P3[t * 3 + 1], n2 = P3[t * 3 + 2];
  float dn0 = P3[192], dn1 = P3[193], dn2 = P3[194];

  int span = 0;
  if (s1 > s0) span = ((s1 - 1) >> 8) - (s0 >> 8) + 1;
  const int kmax = span < (KSLOT - 1) ? span : (KSLOT - 1);
  for (int k = 0; k < kmax; ++k) {
    const float* P = partials + ((size_t)k * n_graphs + g) * PSTRIDE;
    n0 += P[t * 3 + 0]; n1 += P[t * 3 + 1]; n2 += P[t * 3 + 2];
    dn0 += P[192]; dn1 += P[193]; dn2 += P[194];
  }
  float* og = out + (size_t)g * (NFEA * NHEAD);
  og[t * 3 + 0] = dn0 > 0.f ? n0 / dn0 : 0.f;   // empty graph -> 0 (matches ref)
  og[t * 3 + 1] = dn1 > 0.f ? n1 / dn1 : 0.f;
  og[t * 3 + 2] = dn2 > 0.f ? n2 / dn2 : 0.f;
}

extern "C" void kernel_launch(void* const* d_in, const int* in_sizes, int n_in,
                              void* d_out, int out_size, void* d_ws, size_t ws_size,
                              hipStream_t stream)
{
  const float* atom_feas = (const float*)d_in[0];
  const int*   owner     = (const int*)d_in[1];
  const float* W1        = (const float*)d_in[2];
  const float* b1        = (const float*)d_in[3];
  const float* W2        = (const float*)d_in[4];
  const float* b2        = (const float*)d_in[5];
  float* out = (float*)d_out;

  const int n_atoms  = in_sizes[1];
  const int n_graphs = out_size / (NFEA * NHEAD);

  // ws layout: starts[n_graphs+1] ints | pad 256B | partials[KSLOT][G][PSTRIDE]
  int* starts = (int*)d_ws;
  const size_t par_off = (((size_t)(n_graphs + 1) * sizeof(int)) + 255) & ~(size_t)255;
  float* partials = (float*)((char*)d_ws + par_off);

  // zero ONLY the overflow plane (slots 0..2 are fully overwritten where read)
  hipMemsetAsync(partials + (size_t)(KSLOT - 1) * n_graphs * PSTRIDE, 0,
                 (size_t)n_graphs * PSTRIDE * sizeof(float), stream);

  hipLaunchKernelGGL(gar_starts, dim3((n_atoms + 255) / 256), dim3(256), 0, stream,
                     owner, starts, n_atoms, n_graphs);
  hipLaunchKernelGGL(gar_fused, dim3((n_atoms + 255) / 256), dim3(256), 0, stream,
                     atom_feas, owner, starts, W1, b1, W2, b2, partials,
                     n_atoms, n_graphs);
  hipLaunchKernelGGL(gar_reduce, dim3((n_graphs + 3) / 4), dim3(256), 0, stream,
                     starts, partials, out, n_graphs);
}